// Round 7
// baseline (1472.523 us; speedup 1.0000x reference)
//
#include <hip/hip_runtime.h>
#include <hip/hip_bf16.h>
#include <math.h>

// dims
constexpr int B_   = 2;
constexpr int L_   = 512;
constexpr int LP1  = 513;
constexpr int D_   = 512;
constexpr int H_   = 8;
constexpr int HD_  = 64;
constexpr int FF_  = 2048;
constexpr int RFFD = 32;
constexpr int RBH  = 64;
constexpr int M_   = B_ * LP1;     // 1026
constexpr float EPS_ = 1e-5f;
constexpr int NT_  = 8193;         // bias table entries over ds in [-1,1]

// ws layout (floats), overlays:
constexpr size_t OFFZ   = 0;
constexpr size_t OFFX1  = OFFZ  + (size_t)M_ * D_;          // 525,312
constexpr size_t OFFQKV = OFFX1 + (size_t)M_ * D_;          // 1,050,624
constexpr size_t OFFKT  = OFFQKV + (size_t)M_ * 3 * D_;     // 2,626,560
constexpr size_t OFFA   = OFFKT + (size_t)B_ * D_ * LP1;    // 3,151,872
constexpr size_t OFFT   = OFFA + (size_t)M_ * D_;           // 3,677,184
// + NT_*8 = 65,544 -> total 3,742,728 floats = 15.0 MB

__device__ __forceinline__ float gelu_exact(float x) {
    return 0.5f * x * (1.0f + erff(x * 0.70710678118654752f));
}

// ---------------- bias table: table[idx][h] = biasMLP(ds(idx))[h] ----------------
__global__ void k_btab(const float* __restrict__ rff, const float* __restrict__ w1,
                       const float* __restrict__ b1, const float* __restrict__ w2,
                       const float* __restrict__ b2, float* __restrict__ table) {
    const int idx = blockIdx.x * 256 + threadIdx.x;
    if (idx >= NT_) return;
    const float ds = (float)idx * (2.0f / (NT_ - 1)) - 1.0f;
    float feat[RFFD];
    #pragma unroll
    for (int k = 0; k < RFFD; ++k) feat[k] = sinf(ds * rff[k]);
    float bh[H_];
    #pragma unroll
    for (int h = 0; h < H_; ++h) bh[h] = b2[h];
    for (int l = 0; l < RBH; ++l) {
        float acc = b1[l];
        #pragma unroll
        for (int k = 0; k < RFFD; ++k) acc += feat[k] * w1[l * RFFD + k];
        const float gl = gelu_exact(acc);
        #pragma unroll
        for (int h = 0; h < H_; ++h) bh[h] += gl * w2[h * RBH + l];
    }
    #pragma unroll
    for (int h = 0; h < H_; ++h) table[(size_t)idx * H_ + h] = bh[h];
}

// ---------------- LayerNorm: one block (256) per token ----------------
__global__ void k_ln(const float* __restrict__ x, const float* __restrict__ g,
                     const float* __restrict__ be, float* __restrict__ out) {
    const int m = blockIdx.x;
    const int t = threadIdx.x;
    __shared__ float red[256];
    const float v0 = x[(size_t)m * D_ + t];
    const float v1 = x[(size_t)m * D_ + t + 256];
    red[t] = v0 + v1;
    __syncthreads();
    for (int off = 128; off > 0; off >>= 1) {
        if (t < off) red[t] += red[t + off];
        __syncthreads();
    }
    const float mu = red[0] * (1.0f / D_);
    __syncthreads();
    const float d0 = v0 - mu, d1 = v1 - mu;
    red[t] = d0 * d0 + d1 * d1;
    __syncthreads();
    for (int off = 128; off > 0; off >>= 1) {
        if (t < off) red[t] += red[t + off];
        __syncthreads();
    }
    const float rstd = rsqrtf(red[0] * (1.0f / D_) + EPS_);
    out[(size_t)m * D_ + t]       = d0 * rstd * g[t]       + be[t];
    out[(size_t)m * D_ + t + 256] = d1 * rstd * g[t + 256] + be[t + 256];
}

// ---------------- tiled f32 GEMM: C = act(A @ W^T + b) (+res) ----------------
// BN=64, BK=16, 256 threads. BM=64 (4x4/thread) or BM=32 (2x4/thread, 2x grid).
template <int ACT, bool RES, int BM>
__global__ __launch_bounds__(256)
void k_gemm_t(const float* __restrict__ A, const float* __restrict__ W,
              const float* __restrict__ bias, const float* __restrict__ res,
              float* __restrict__ C, int M, int N, int K) {
    constexpr int BN = 64, BK = 16;
    constexpr int RM = BM / 16;
    __shared__ float As[BK][BM + 4];
    __shared__ float Bs[BK][BN + 4];
    const int t  = threadIdx.x;
    const int tx = t & 15;
    const int ty = t >> 4;
    const int m0 = blockIdx.y * BM;
    const int n0 = blockIdx.x * BN;
    float acc[RM][4] = {};

    for (int k0 = 0; k0 < K; k0 += BK) {
        if (t < BM * 4) {
            const int lr = t >> 2, lf = t & 3;
            const int gm = m0 + lr;
            float4 v = make_float4(0.f, 0.f, 0.f, 0.f);
            if (gm < M) v = *(const float4*)&A[(size_t)gm * K + k0 + lf * 4];
            As[lf * 4 + 0][lr] = v.x; As[lf * 4 + 1][lr] = v.y;
            As[lf * 4 + 2][lr] = v.z; As[lf * 4 + 3][lr] = v.w;
        }
        {
            const int lr = t >> 2, lf = t & 3;
            const float4 v = *(const float4*)&W[(size_t)(n0 + lr) * K + k0 + lf * 4];
            Bs[lf * 4 + 0][lr] = v.x; Bs[lf * 4 + 1][lr] = v.y;
            Bs[lf * 4 + 2][lr] = v.z; Bs[lf * 4 + 3][lr] = v.w;
        }
        __syncthreads();
        #pragma unroll
        for (int k = 0; k < BK; ++k) {
            float am[RM];
            if constexpr (RM == 4) {
                const float4 av = *(const float4*)&As[k][ty * 4];
                am[0] = av.x; am[1] = av.y; am[2] = av.z; am[3] = av.w;
            } else {
                const float2 av = *(const float2*)&As[k][ty * 2];
                am[0] = av.x; am[1] = av.y;
            }
            const float4 bv = *(const float4*)&Bs[k][tx * 4];
            const float bn[4] = {bv.x, bv.y, bv.z, bv.w};
            #pragma unroll
            for (int i = 0; i < RM; ++i)
                #pragma unroll
                for (int j = 0; j < 4; ++j) acc[i][j] += am[i] * bn[j];
        }
        __syncthreads();
    }

    const float4 bb = *(const float4*)&bias[n0 + tx * 4];
    const float bv[4] = {bb.x, bb.y, bb.z, bb.w};
    #pragma unroll
    for (int i = 0; i < RM; ++i) {
        const int gm = m0 + ty * RM + i;
        if (gm < M) {
            float4 o;
            float* op = (float*)&o;
            #pragma unroll
            for (int j = 0; j < 4; ++j) {
                float v = acc[i][j] + bv[j];
                if (ACT == 1) v = gelu_exact(v);
                op[j] = v;
            }
            if (RES) {
                const float4 r = *(const float4*)&res[(size_t)gm * N + n0 + tx * 4];
                o.x += r.x; o.y += r.y; o.z += r.z; o.w += r.w;
            }
            *(float4*)&C[(size_t)gm * N + n0 + tx * 4] = o;
        }
    }
}

// ---------------- kT[b][d][j] = qkv[b][j][D + d]  (32x32 LDS tiles) ----------------
__global__ void k_kT(const float* __restrict__ qkv, float* __restrict__ kT) {
    __shared__ float tile[32][33];
    const int b  = blockIdx.z;
    const int j0 = blockIdx.x * 32;
    const int d0 = blockIdx.y * 32;
    const int tx = threadIdx.x;
    const int ty = threadIdx.y;
    #pragma unroll
    for (int q = 0; q < 4; ++q) {
        const int j = j0 + ty + q * 8;
        if (j < LP1)
            tile[ty + q * 8][tx] = qkv[((size_t)(b * LP1 + j)) * (3 * D_) + D_ + d0 + tx];
    }
    __syncthreads();
    #pragma unroll
    for (int q = 0; q < 4; ++q) {
        const int j = j0 + tx;
        const int d = d0 + ty + q * 8;
        if (j < LP1)
            kT[((size_t)b * D_ + d) * LP1 + j] = tile[tx][ty + q * 8];
    }
}

// ---------------- attention core: table-bias + scores + softmax + PV -> a ----------
// one block (256) per query token m=(b,i)
__global__ __launch_bounds__(256)
void k_attn(const float* __restrict__ qkv, const float* __restrict__ kT,
            const float* __restrict__ s_norm, const float* __restrict__ table,
            float* __restrict__ a) {
    const int m = blockIdx.x;
    const int b = m / LP1;
    const int i = m % LP1;
    const int t = threadIdx.x;
    __shared__ float q_s[D_];
    __shared__ float p_s[H_][LP1 + 3];

    q_s[t]       = qkv[(size_t)m * (3 * D_) + t];
    q_s[t + 256] = qkv[(size_t)m * (3 * D_) + t + 256];
    const float s_i = (i == 0) ? 0.f : s_norm[b * L_ + i - 1];
    __syncthreads();

    // scores: p_s[h][j] = tableLerp(s_i - s_j)[h] + (q_h . k_h)/8
    for (int j = t; j < LP1; j += 256) {
        const float s_j = (j == 0) ? 0.f : s_norm[b * L_ + j - 1];
        const float ds = s_i - s_j;
        float u = (ds + 1.0f) * ((NT_ - 1) * 0.5f);
        u = fminf(fmaxf(u, 0.0f), (float)(NT_ - 2));
        const int i0 = (int)u;
        const float f = u - (float)i0;
        const float* tp = &table[(size_t)i0 * H_];
        const float4 a0 = *(const float4*)&tp[0];
        const float4 a1 = *(const float4*)&tp[4];
        const float4 c0 = *(const float4*)&tp[8];
        const float4 c1 = *(const float4*)&tp[12];
        float bh[H_];
        bh[0] = a0.x + f * (c0.x - a0.x); bh[1] = a0.y + f * (c0.y - a0.y);
        bh[2] = a0.z + f * (c0.z - a0.z); bh[3] = a0.w + f * (c0.w - a0.w);
        bh[4] = a1.x + f * (c1.x - a1.x); bh[5] = a1.y + f * (c1.y - a1.y);
        bh[6] = a1.z + f * (c1.z - a1.z); bh[7] = a1.w + f * (c1.w - a1.w);
        const float* ktb = kT + (size_t)b * D_ * LP1 + j;
        #pragma unroll
        for (int h = 0; h < H_; ++h) {
            float dot = 0.f;
            #pragma unroll
            for (int d4 = 0; d4 < HD_; d4 += 4) {
                const float4 q4 = *(const float4*)&q_s[h * HD_ + d4];
                dot += q4.x * ktb[(size_t)(h * HD_ + d4 + 0) * LP1];
                dot += q4.y * ktb[(size_t)(h * HD_ + d4 + 1) * LP1];
                dot += q4.z * ktb[(size_t)(h * HD_ + d4 + 2) * LP1];
                dot += q4.w * ktb[(size_t)(h * HD_ + d4 + 3) * LP1];
            }
            p_s[h][j] = bh[h] + 0.125f * dot;
        }
    }
    __syncthreads();

    // softmax: 8 parallel 32-lane groups, one head each
    {
        const int g  = t >> 5;
        const int sl = t & 31;
        float mx = -1e30f;
        for (int j = sl; j < LP1; j += 32) mx = fmaxf(mx, p_s[g][j]);
        #pragma unroll
        for (int off = 16; off > 0; off >>= 1) mx = fmaxf(mx, __shfl_xor(mx, off, 32));
        float sum = 0.f;
        for (int j = sl; j < LP1; j += 32) {
            const float e = __expf(p_s[g][j] - mx);
            p_s[g][j] = e;
            sum += e;
        }
        #pragma unroll
        for (int off = 16; off > 0; off >>= 1) sum += __shfl_xor(sum, off, 32);
        const float inv = 1.0f / sum;
        for (int j = sl; j < LP1; j += 32) p_s[g][j] *= inv;
    }
    __syncthreads();

    // PV: a[m,e] = sum_j p[h(e)][j] * v[b,j,e]
    const float* vbase = qkv + (size_t)(b * LP1) * (3 * D_) + 2 * D_;
    for (int e = t; e < D_; e += 256) {
        const int h = e >> 6;
        float acc2 = 0.f;
        for (int j = 0; j < LP1; ++j) acc2 += p_s[h][j] * vbase[(size_t)j * (3 * D_) + e];
        a[(size_t)m * D_ + e] = acc2;
    }
}

extern "C" void kernel_launch(void* const* d_in, const int* in_sizes, int n_in,
                              void* d_out, int out_size, void* d_ws, size_t ws_size,
                              hipStream_t stream) {
    const float* x      = (const float*)d_in[0];
    const float* s_norm = (const float*)d_in[1];
    const float* rff    = (const float*)d_in[2];
    const float* rb_w1  = (const float*)d_in[3];
    const float* rb_b1  = (const float*)d_in[4];
    const float* rb_w2  = (const float*)d_in[5];
    const float* rb_b2  = (const float*)d_in[6];
    const float* n1_g   = (const float*)d_in[7];
    const float* n1_b   = (const float*)d_in[8];
    const float* n2_g   = (const float*)d_in[9];
    const float* n2_b   = (const float*)d_in[10];
    const float* in_w   = (const float*)d_in[11];
    const float* in_b   = (const float*)d_in[12];
    const float* out_w  = (const float*)d_in[13];
    const float* out_b  = (const float*)d_in[14];
    const float* ff_w1  = (const float*)d_in[15];
    const float* ff_b1  = (const float*)d_in[16];
    const float* ff_w2  = (const float*)d_in[17];
    const float* ff_b2  = (const float*)d_in[18];

    float* ws    = (float*)d_ws;
    float* z     = ws + OFFZ;      // reused as h2
    float* x1    = ws + OFFX1;
    float* qkv   = ws + OFFQKV;
    float* kT    = ws + OFFKT;
    float* a     = ws + OFFA;
    float* table = ws + OFFT;
    float* h2    = z;
    float* hact  = qkv;            // overlays qkv+kT (both dead by FF phase)

    // 0) bias table
    k_btab<<<(NT_ + 255) / 256, 256, 0, stream>>>(rff, rb_w1, rb_b1, rb_w2, rb_b2, table);
    // 1) LN1 -> z
    k_ln<<<M_, 256, 0, stream>>>(x, n1_g, n1_b, z);
    // 2) qkv = z @ in_w^T + in_b
    k_gemm_t<0, false, 64><<<dim3(3 * D_ / 64, (M_ + 63) / 64), 256, 0, stream>>>(
        z, in_w, in_b, nullptr, qkv, M_, 3 * D_, D_);
    // 3) kT = transpose of K part
    k_kT<<<dim3((LP1 + 31) / 32, D_ / 32, B_), dim3(32, 8), 0, stream>>>(qkv, kT);
    // 4) attention core -> a
    k_attn<<<M_, 256, 0, stream>>>(qkv, kT, s_norm, table, a);
    // 5) x1 = x + a @ out_w^T + out_b   (BM=32 -> 264 blocks)
    k_gemm_t<0, true, 32><<<dim3(D_ / 64, (M_ + 31) / 32), 256, 0, stream>>>(
        a, out_w, out_b, x, x1, M_, D_, D_);
    // 6) LN2 -> h2
    k_ln<<<M_, 256, 0, stream>>>(x1, n2_g, n2_b, h2);
    // 7) hact = gelu(h2 @ ff_w1^T + ff_b1)
    k_gemm_t<1, false, 64><<<dim3(FF_ / 64, (M_ + 63) / 64), 256, 0, stream>>>(
        h2, ff_w1, ff_b1, nullptr, hact, M_, FF_, D_);
    // 8) out = x1 + hact @ ff_w2^T + ff_b2   (BM=32 -> 264 blocks)
    k_gemm_t<0, true, 32><<<dim3(D_ / 64, (M_ + 31) / 32), 256, 0, stream>>>(
        hact, ff_w2, ff_b2, x1, (float*)d_out, M_, D_, FF_);
}

// Round 8
// 463.378 us; speedup vs baseline: 3.1778x; 3.1778x over previous
//
#include <hip/hip_runtime.h>
#include <hip/hip_bf16.h>
#include <math.h>

// dims
constexpr int B_   = 2;
constexpr int L_   = 512;
constexpr int LP1  = 513;
constexpr int D_   = 512;
constexpr int H_   = 8;
constexpr int HD_  = 64;
constexpr int FF_  = 2048;
constexpr int RFFD = 32;
constexpr int RBH  = 64;
constexpr int M_   = B_ * LP1;     // 1026
constexpr float EPS_ = 1e-5f;
constexpr int NT_  = 8193;         // bias table entries over ds in [-1,1]

// ws layout (floats), overlays:
constexpr size_t OFFZ   = 0;
constexpr size_t OFFX1  = OFFZ  + (size_t)M_ * D_;          // 525,312
constexpr size_t OFFQKV = OFFX1 + (size_t)M_ * D_;          // 1,050,624
constexpr size_t OFFKT  = OFFQKV + (size_t)M_ * 3 * D_;     // 2,626,560
constexpr size_t OFFA   = OFFKT + (size_t)B_ * D_ * LP1;    // 3,151,872
constexpr size_t OFFT   = OFFA + (size_t)M_ * D_;           // 3,677,184
// + NT_*8 = 65,544 -> total 3,742,728 floats = 15.0 MB

__device__ __forceinline__ float gelu_exact(float x) {
    return 0.5f * x * (1.0f + erff(x * 0.70710678118654752f));
}

// ---------------- bias table: table[idx][h] = biasMLP(ds(idx))[h] ----------------
__global__ void k_btab(const float* __restrict__ rff, const float* __restrict__ w1,
                       const float* __restrict__ b1, const float* __restrict__ w2,
                       const float* __restrict__ b2, float* __restrict__ table) {
    const int idx = blockIdx.x * 256 + threadIdx.x;
    if (idx >= NT_) return;
    const float ds = (float)idx * (2.0f / (NT_ - 1)) - 1.0f;
    float feat[RFFD];
    #pragma unroll
    for (int k = 0; k < RFFD; ++k) feat[k] = sinf(ds * rff[k]);
    float bh[H_];
    #pragma unroll
    for (int h = 0; h < H_; ++h) bh[h] = b2[h];
    for (int l = 0; l < RBH; ++l) {
        float acc = b1[l];
        #pragma unroll
        for (int k = 0; k < RFFD; ++k) acc += feat[k] * w1[l * RFFD + k];
        const float gl = gelu_exact(acc);
        #pragma unroll
        for (int h = 0; h < H_; ++h) bh[h] += gl * w2[h * RBH + l];
    }
    #pragma unroll
    for (int h = 0; h < H_; ++h) table[(size_t)idx * H_ + h] = bh[h];
}

// ---------------- LayerNorm: one block (256) per token ----------------
__global__ void k_ln(const float* __restrict__ x, const float* __restrict__ g,
                     const float* __restrict__ be, float* __restrict__ out) {
    const int m = blockIdx.x;
    const int t = threadIdx.x;
    __shared__ float red[256];
    const float v0 = x[(size_t)m * D_ + t];
    const float v1 = x[(size_t)m * D_ + t + 256];
    red[t] = v0 + v1;
    __syncthreads();
    for (int off = 128; off > 0; off >>= 1) {
        if (t < off) red[t] += red[t + off];
        __syncthreads();
    }
    const float mu = red[0] * (1.0f / D_);
    __syncthreads();
    const float d0 = v0 - mu, d1 = v1 - mu;
    red[t] = d0 * d0 + d1 * d1;
    __syncthreads();
    for (int off = 128; off > 0; off >>= 1) {
        if (t < off) red[t] += red[t + off];
        __syncthreads();
    }
    const float rstd = rsqrtf(red[0] * (1.0f / D_) + EPS_);
    out[(size_t)m * D_ + t]       = d0 * rstd * g[t]       + be[t];
    out[(size_t)m * D_ + t + 256] = d1 * rstd * g[t + 256] + be[t + 256];
}

// ---------------- tiled f32 GEMM: C = act(A @ W^T + b) (+res) ----------------
template <int ACT, bool RES, int BM>
__global__ __launch_bounds__(256)
void k_gemm_t(const float* __restrict__ A, const float* __restrict__ W,
              const float* __restrict__ bias, const float* __restrict__ res,
              float* __restrict__ C, int M, int N, int K) {
    constexpr int BN = 64, BK = 16;
    constexpr int RM = BM / 16;
    __shared__ float As[BK][BM + 4];
    __shared__ float Bs[BK][BN + 4];
    const int t  = threadIdx.x;
    const int tx = t & 15;
    const int ty = t >> 4;
    const int m0 = blockIdx.y * BM;
    const int n0 = blockIdx.x * BN;
    float acc[RM][4] = {};

    for (int k0 = 0; k0 < K; k0 += BK) {
        if (t < BM * 4) {
            const int lr = t >> 2, lf = t & 3;
            const int gm = m0 + lr;
            float4 v = make_float4(0.f, 0.f, 0.f, 0.f);
            if (gm < M) v = *(const float4*)&A[(size_t)gm * K + k0 + lf * 4];
            As[lf * 4 + 0][lr] = v.x; As[lf * 4 + 1][lr] = v.y;
            As[lf * 4 + 2][lr] = v.z; As[lf * 4 + 3][lr] = v.w;
        }
        {
            const int lr = t >> 2, lf = t & 3;
            const float4 v = *(const float4*)&W[(size_t)(n0 + lr) * K + k0 + lf * 4];
            Bs[lf * 4 + 0][lr] = v.x; Bs[lf * 4 + 1][lr] = v.y;
            Bs[lf * 4 + 2][lr] = v.z; Bs[lf * 4 + 3][lr] = v.w;
        }
        __syncthreads();
        #pragma unroll
        for (int k = 0; k < BK; ++k) {
            float am[RM];
            if constexpr (RM == 4) {
                const float4 av = *(const float4*)&As[k][ty * 4];
                am[0] = av.x; am[1] = av.y; am[2] = av.z; am[3] = av.w;
            } else {
                const float2 av = *(const float2*)&As[k][ty * 2];
                am[0] = av.x; am[1] = av.y;
            }
            const float4 bv = *(const float4*)&Bs[k][tx * 4];
            const float bn[4] = {bv.x, bv.y, bv.z, bv.w};
            #pragma unroll
            for (int i = 0; i < RM; ++i)
                #pragma unroll
                for (int j = 0; j < 4; ++j) acc[i][j] += am[i] * bn[j];
        }
        __syncthreads();
    }

    const float4 bb = *(const float4*)&bias[n0 + tx * 4];
    const float bv[4] = {bb.x, bb.y, bb.z, bb.w};
    #pragma unroll
    for (int i = 0; i < RM; ++i) {
        const int gm = m0 + ty * RM + i;
        if (gm < M) {
            float4 o;
            float* op = (float*)&o;
            #pragma unroll
            for (int j = 0; j < 4; ++j) {
                float v = acc[i][j] + bv[j];
                if (ACT == 1) v = gelu_exact(v);
                op[j] = v;
            }
            if (RES) {
                const float4 r = *(const float4*)&res[(size_t)gm * N + n0 + tx * 4];
                o.x += r.x; o.y += r.y; o.z += r.z; o.w += r.w;
            }
            *(float4*)&C[(size_t)gm * N + n0 + tx * 4] = o;
        }
    }
}

// ---------------- kT[b][d][j] = qkv[b][j][D + d]  (32x32 LDS tiles) ----------------
__global__ void k_kT(const float* __restrict__ qkv, float* __restrict__ kT) {
    __shared__ float tile[32][33];
    const int b  = blockIdx.z;
    const int j0 = blockIdx.x * 32;
    const int d0 = blockIdx.y * 32;
    const int tx = threadIdx.x;
    const int ty = threadIdx.y;
    #pragma unroll
    for (int q = 0; q < 4; ++q) {
        const int j = j0 + ty + q * 8;
        if (j < LP1)
            tile[ty + q * 8][tx] = qkv[((size_t)(b * LP1 + j)) * (3 * D_) + D_ + d0 + tx];
    }
    __syncthreads();
    #pragma unroll
    for (int q = 0; q < 4; ++q) {
        const int j = j0 + tx;
        const int d = d0 + ty + q * 8;
        if (j < LP1)
            kT[((size_t)b * D_ + d) * LP1 + j] = tile[tx][ty + q * 8];
    }
}

// ---------------- attention core: 32-lane group per head, j-register tile ----------
// one block (256) per query token m=(b,i); group g owns head g.
__global__ __launch_bounds__(256)
void k_attn(const float* __restrict__ qkv, const float* __restrict__ kT,
            const float* __restrict__ s_norm, const float* __restrict__ table,
            float* __restrict__ a) {
    const int m = blockIdx.x;
    const int b = m / LP1;
    const int i = m % LP1;
    const int t = threadIdx.x;
    __shared__ float q_s[D_];
    __shared__ float s_s[LP1 + 3];
    __shared__ float p_s[H_][LP1 + 3];

    q_s[t]       = qkv[(size_t)m * (3 * D_) + t];
    q_s[t + 256] = qkv[(size_t)m * (3 * D_) + t + 256];
    for (int j = t; j < LP1; j += 256)
        s_s[j] = (j == 0) ? 0.f : s_norm[b * L_ + j - 1];
    const float s_i = (i == 0) ? 0.f : s_norm[b * L_ + i - 1];
    __syncthreads();

    const int g  = t >> 5;    // head
    const int sl = t & 31;    // lane in group
    constexpr int NJ = 17;    // ceil(513/32)

    // QK^T: acc[jj] = q_g . k_g[:, sl+32*jj]
    float acc[NJ];
    #pragma unroll
    for (int jj = 0; jj < NJ; ++jj) acc[jj] = 0.f;
    const float* kTg = kT + ((size_t)b * D_ + g * HD_) * LP1;
    for (int dd = 0; dd < HD_; ++dd) {
        const float qv = q_s[g * HD_ + dd];          // LDS broadcast
        const float* row = kTg + (size_t)dd * LP1;
        #pragma unroll
        for (int jj = 0; jj < NJ; ++jj) {
            const int j = sl + jj * 32;
            const float kv = (j < LP1) ? row[j] : 0.f;   // OOB lands in next ws buf: safe
            acc[jj] = fmaf(qv, kv, acc[jj]);
        }
    }

    // bias lerp + scores (kept in registers), group max
    float mx = -1e30f;
    #pragma unroll
    for (int jj = 0; jj < NJ; ++jj) {
        const int j = sl + jj * 32;
        if (j < LP1) {
            const float ds = s_i - s_s[j];
            float u = (ds + 1.0f) * ((NT_ - 1) * 0.5f);
            u = fminf(fmaxf(u, 0.0f), (float)(NT_ - 2));
            const int i0 = (int)u;
            const float f = u - (float)i0;
            const float b0  = table[(size_t)i0 * H_ + g];
            const float b1v = table[(size_t)(i0 + 1) * H_ + g];
            acc[jj] = b0 + f * (b1v - b0) + 0.125f * acc[jj];
            mx = fmaxf(mx, acc[jj]);
        }
    }
    #pragma unroll
    for (int off = 16; off > 0; off >>= 1) mx = fmaxf(mx, __shfl_xor(mx, off, 32));
    float sum = 0.f;
    #pragma unroll
    for (int jj = 0; jj < NJ; ++jj) {
        const int j = sl + jj * 32;
        if (j < LP1) {
            acc[jj] = __expf(acc[jj] - mx);
            sum += acc[jj];
        }
    }
    #pragma unroll
    for (int off = 16; off > 0; off >>= 1) sum += __shfl_xor(sum, off, 32);
    const float inv = 1.0f / sum;
    #pragma unroll
    for (int jj = 0; jj < NJ; ++jj) {
        const int j = sl + jj * 32;
        if (j < LP1) p_s[g][j] = acc[jj] * inv;
    }
    __syncthreads();

    // PV: a[m,e] = sum_j p[h(e)][j] * v[b,j,e]  (coalesced v reads, 4-way ILP)
    const float* vbase = qkv + (size_t)(b * LP1) * (3 * D_) + 2 * D_;
    for (int e = t; e < D_; e += 256) {
        const int h = e >> 6;
        float a0 = 0.f, a1 = 0.f, a2 = 0.f, a3 = 0.f;
        int j = 0;
        for (; j + 4 <= LP1; j += 4) {
            a0 = fmaf(p_s[h][j + 0], vbase[(size_t)(j + 0) * (3 * D_) + e], a0);
            a1 = fmaf(p_s[h][j + 1], vbase[(size_t)(j + 1) * (3 * D_) + e], a1);
            a2 = fmaf(p_s[h][j + 2], vbase[(size_t)(j + 2) * (3 * D_) + e], a2);
            a3 = fmaf(p_s[h][j + 3], vbase[(size_t)(j + 3) * (3 * D_) + e], a3);
        }
        for (; j < LP1; ++j)
            a0 = fmaf(p_s[h][j], vbase[(size_t)j * (3 * D_) + e], a0);
        a[(size_t)m * D_ + e] = (a0 + a1) + (a2 + a3);
    }
}

extern "C" void kernel_launch(void* const* d_in, const int* in_sizes, int n_in,
                              void* d_out, int out_size, void* d_ws, size_t ws_size,
                              hipStream_t stream) {
    const float* x      = (const float*)d_in[0];
    const float* s_norm = (const float*)d_in[1];
    const float* rff    = (const float*)d_in[2];
    const float* rb_w1  = (const float*)d_in[3];
    const float* rb_b1  = (const float*)d_in[4];
    const float* rb_w2  = (const float*)d_in[5];
    const float* rb_b2  = (const float*)d_in[6];
    const float* n1_g   = (const float*)d_in[7];
    const float* n1_b   = (const float*)d_in[8];
    const float* n2_g   = (const float*)d_in[9];
    const float* n2_b   = (const float*)d_in[10];
    const float* in_w   = (const float*)d_in[11];
    const float* in_b   = (const float*)d_in[12];
    const float* out_w  = (const float*)d_in[13];
    const float* out_b  = (const float*)d_in[14];
    const float* ff_w1  = (const float*)d_in[15];
    const float* ff_b1  = (const float*)d_in[16];
    const float* ff_w2  = (const float*)d_in[17];
    const float* ff_b2  = (const float*)d_in[18];

    float* ws    = (float*)d_ws;
    float* z     = ws + OFFZ;      // reused as h2
    float* x1    = ws + OFFX1;
    float* qkv   = ws + OFFQKV;
    float* kT    = ws + OFFKT;
    float* a     = ws + OFFA;
    float* table = ws + OFFT;
    float* h2    = z;
    float* hact  = qkv;            // overlays qkv+kT (both dead by FF phase)

    // 0) bias table
    k_btab<<<(NT_ + 255) / 256, 256, 0, stream>>>(rff, rb_w1, rb_b1, rb_w2, rb_b2, table);
    // 1) LN1 -> z
    k_ln<<<M_, 256, 0, stream>>>(x, n1_g, n1_b, z);
    // 2) qkv = z @ in_w^T + in_b
    k_gemm_t<0, false, 64><<<dim3(3 * D_ / 64, (M_ + 63) / 64), 256, 0, stream>>>(
        z, in_w, in_b, nullptr, qkv, M_, 3 * D_, D_);
    // 3) kT = transpose of K part
    k_kT<<<dim3((LP1 + 31) / 32, D_ / 32, B_), dim3(32, 8), 0, stream>>>(qkv, kT);
    // 4) attention core -> a
    k_attn<<<M_, 256, 0, stream>>>(qkv, kT, s_norm, table, a);
    // 5) x1 = x + a @ out_w^T + out_b   (BM=32 -> 264 blocks)
    k_gemm_t<0, true, 32><<<dim3(D_ / 64, (M_ + 31) / 32), 256, 0, stream>>>(
        a, out_w, out_b, x, x1, M_, D_, D_);
    // 6) LN2 -> h2
    k_ln<<<M_, 256, 0, stream>>>(x1, n2_g, n2_b, h2);
    // 7) hact = gelu(h2 @ ff_w1^T + ff_b1)
    k_gemm_t<1, false, 64><<<dim3(FF_ / 64, (M_ + 63) / 64), 256, 0, stream>>>(
        h2, ff_w1, ff_b1, nullptr, hact, M_, FF_, D_);
    // 8) out = x1 + hact @ ff_w2^T + ff_b2   (BM=32 -> 264 blocks)
    k_gemm_t<0, true, 32><<<dim3(D_ / 64, (M_ + 31) / 32), 256, 0, stream>>>(
        hact, ff_w2, ff_b2, x1, (float*)d_out, M_, D_, FF_);
}

// Round 11
// 372.036 us; speedup vs baseline: 3.9580x; 1.2455x over previous
//
#include <hip/hip_runtime.h>
#include <hip/hip_bf16.h>
#include <math.h>

// dims
constexpr int B_   = 2;
constexpr int L_   = 512;
constexpr int LP1  = 513;
constexpr int D_   = 512;
constexpr int H_   = 8;
constexpr int HD_  = 64;
constexpr int FF_  = 2048;
constexpr int RFFD = 32;
constexpr int RBH  = 64;
constexpr int M_   = B_ * LP1;     // 1026
constexpr float EPS_ = 1e-5f;
constexpr int NT_  = 8193;         // bias table entries over ds in [-1,1]

// ws layout (floats), overlays:
constexpr size_t OFFZ   = 0;
constexpr size_t OFFX1  = OFFZ  + (size_t)M_ * D_;          // 525,312
constexpr size_t OFFQKV = OFFX1 + (size_t)M_ * D_;          // 1,050,624
constexpr size_t OFFKT  = OFFQKV + (size_t)M_ * 3 * D_;     // 2,626,560
constexpr size_t OFFA   = OFFKT + (size_t)B_ * D_ * LP1;    // 3,151,872
constexpr size_t OFFT   = OFFA + (size_t)M_ * D_;           // 3,677,184
// + NT_*8 = 65,544 -> total 3,742,728 floats = 15.0 MB

typedef __attribute__((ext_vector_type(4))) float f32x4;
typedef __attribute__((ext_vector_type(8))) __bf16 bf16x8;
typedef __attribute__((ext_vector_type(4))) __bf16 bf16x4;

__device__ __forceinline__ float gelu_exact(float x) {
    return 0.5f * x * (1.0f + erff(x * 0.70710678118654752f));
}

__device__ __forceinline__ __bf16 f2b(float f) {
    union { float f; unsigned u; } a; a.f = f;
    const unsigned r = (a.u + 0x7FFFu + ((a.u >> 16) & 1u)) >> 16;   // RNE
    union { unsigned short s; __bf16 b; } o; o.s = (unsigned short)r;
    return o.b;
}

// ---------------- bias table: table[idx][h] = biasMLP(ds(idx))[h] ----------------
__global__ void k_btab(const float* __restrict__ rff, const float* __restrict__ w1,
                       const float* __restrict__ b1, const float* __restrict__ w2,
                       const float* __restrict__ b2, float* __restrict__ table) {
    const int idx = blockIdx.x * 256 + threadIdx.x;
    if (idx >= NT_) return;
    const float ds = (float)idx * (2.0f / (NT_ - 1)) - 1.0f;
    float feat[RFFD];
    #pragma unroll
    for (int k = 0; k < RFFD; ++k) feat[k] = sinf(ds * rff[k]);
    float bh[H_];
    #pragma unroll
    for (int h = 0; h < H_; ++h) bh[h] = b2[h];
    for (int l = 0; l < RBH; ++l) {
        float acc = b1[l];
        #pragma unroll
        for (int k = 0; k < RFFD; ++k) acc += feat[k] * w1[l * RFFD + k];
        const float gl = gelu_exact(acc);
        #pragma unroll
        for (int h = 0; h < H_; ++h) bh[h] += gl * w2[h * RBH + l];
    }
    #pragma unroll
    for (int h = 0; h < H_; ++h) table[(size_t)idx * H_ + h] = bh[h];
}

// ---------------- LayerNorm: one block (256) per token ----------------
__global__ void k_ln(const float* __restrict__ x, const float* __restrict__ g,
                     const float* __restrict__ be, float* __restrict__ out) {
    const int m = blockIdx.x;
    const int t = threadIdx.x;
    __shared__ float red[256];
    const float v0 = x[(size_t)m * D_ + t];
    const float v1 = x[(size_t)m * D_ + t + 256];
    red[t] = v0 + v1;
    __syncthreads();
    for (int off = 128; off > 0; off >>= 1) {
        if (t < off) red[t] += red[t + off];
        __syncthreads();
    }
    const float mu = red[0] * (1.0f / D_);
    __syncthreads();
    const float d0 = v0 - mu, d1 = v1 - mu;
    red[t] = d0 * d0 + d1 * d1;
    __syncthreads();
    for (int off = 128; off > 0; off >>= 1) {
        if (t < off) red[t] += red[t + off];
        __syncthreads();
    }
    const float rstd = rsqrtf(red[0] * (1.0f / D_) + EPS_);
    out[(size_t)m * D_ + t]       = d0 * rstd * g[t]       + be[t];
    out[(size_t)m * D_ + t + 256] = d1 * rstd * g[t + 256] + be[t + 256];
}

// ---------------- MFMA bf16 GEMM: C = act(A @ W^T + bias) (+res) ----------------
// A [M][K] f32, W [N][K] f32 (torch layout), converted to bf16 in LDS staging.
// BM=BN=64, BK=32, 256 threads = 4 waves; wave (wr,wc) owns a 32x32 quadrant
// computed as 2x2 tiles of v_mfma_f32_16x16x32_bf16.
// Fragment layout: A lane l -> row l&15, k = 8*(l>>4)+j (contiguous 8);
//                  B lane l -> col l&15, same k group;
//                  D lane l, reg v -> row 4*(l>>4)+v, col l&15 (m89-verified).
template <int ACT, bool RES>
__global__ __launch_bounds__(256)
void k_gemm_mfma(const float* __restrict__ A, const float* __restrict__ W,
                 const float* __restrict__ bias, const float* __restrict__ res,
                 float* __restrict__ C, int M, int N, int K) {
    constexpr int BM = 64, BN = 64, BK = 32, PAD = 8;   // row stride 80B (16B-aligned)
    __shared__ __bf16 As[BM][BK + PAD];
    __shared__ __bf16 Bs[BN][BK + PAD];
    const int t    = threadIdx.x;
    const int m0   = blockIdx.y * BM;
    const int n0   = blockIdx.x * BN;
    const int wid  = t >> 6;
    const int lane = t & 63;
    const int wr   = (wid >> 1) * 32;
    const int wc   = (wid & 1) * 32;
    const int fr   = lane & 15;
    const int kg   = lane >> 4;

    f32x4 acc[2][2] = {};

    for (int k0 = 0; k0 < K; k0 += BK) {
        #pragma unroll
        for (int i = 0; i < 2; ++i) {
            const int idx = t + i * 256;       // 512 float4 slots per tile
            const int row = idx >> 3;
            const int f4  = idx & 7;
            // A tile (guard M)
            float4 av = make_float4(0.f, 0.f, 0.f, 0.f);
            const int gm = m0 + row;
            if (gm < M) av = *(const float4*)&A[(size_t)gm * K + k0 + f4 * 4];
            bf16x4 ab;
            ab[0] = f2b(av.x); ab[1] = f2b(av.y); ab[2] = f2b(av.z); ab[3] = f2b(av.w);
            *(bf16x4*)&As[row][f4 * 4] = ab;
            // W tile (N multiple of 64 -> no guard)
            const float4 wv = *(const float4*)&W[(size_t)(n0 + row) * K + k0 + f4 * 4];
            bf16x4 wb;
            wb[0] = f2b(wv.x); wb[1] = f2b(wv.y); wb[2] = f2b(wv.z); wb[3] = f2b(wv.w);
            *(bf16x4*)&Bs[row][f4 * 4] = wb;
        }
        __syncthreads();
        const bf16x8 af0 = *(const bf16x8*)&As[wr + fr][kg * 8];
        const bf16x8 af1 = *(const bf16x8*)&As[wr + 16 + fr][kg * 8];
        const bf16x8 bf0 = *(const bf16x8*)&Bs[wc + fr][kg * 8];
        const bf16x8 bf1 = *(const bf16x8*)&Bs[wc + 16 + fr][kg * 8];
        acc[0][0] = __builtin_amdgcn_mfma_f32_16x16x32_bf16(af0, bf0, acc[0][0], 0, 0, 0);
        acc[0][1] = __builtin_amdgcn_mfma_f32_16x16x32_bf16(af0, bf1, acc[0][1], 0, 0, 0);
        acc[1][0] = __builtin_amdgcn_mfma_f32_16x16x32_bf16(af1, bf0, acc[1][0], 0, 0, 0);
        acc[1][1] = __builtin_amdgcn_mfma_f32_16x16x32_bf16(af1, bf1, acc[1][1], 0, 0, 0);
        __syncthreads();
    }

    #pragma unroll
    for (int ti = 0; ti < 2; ++ti) {
        #pragma unroll
        for (int tj = 0; tj < 2; ++tj) {
            const int gn = n0 + wc + tj * 16 + fr;
            const float bv = bias[gn];
            #pragma unroll
            for (int v = 0; v < 4; ++v) {
                const int gm = m0 + wr + ti * 16 + kg * 4 + v;
                if (gm < M) {
                    float val = acc[ti][tj][v] + bv;
                    if (ACT == 1) val = gelu_exact(val);
                    if (RES) val += res[(size_t)gm * N + gn];
                    C[(size_t)gm * N + gn] = val;
                }
            }
        }
    }
}

// ---------------- kT[b][d][j] = qkv[b][j][D + d]  (32x32 LDS tiles) ----------------
__global__ void k_kT(const float* __restrict__ qkv, float* __restrict__ kT) {
    __shared__ float tile[32][33];
    const int b  = blockIdx.z;
    const int j0 = blockIdx.x * 32;
    const int d0 = blockIdx.y * 32;
    const int tx = threadIdx.x;
    const int ty = threadIdx.y;
    #pragma unroll
    for (int q = 0; q < 4; ++q) {
        const int j = j0 + ty + q * 8;
        if (j < LP1)
            tile[ty + q * 8][tx] = qkv[((size_t)(b * LP1 + j)) * (3 * D_) + D_ + d0 + tx];
    }
    __syncthreads();
    #pragma unroll
    for (int q = 0; q < 4; ++q) {
        const int j = j0 + tx;
        const int d = d0 + ty + q * 8;
        if (j < LP1)
            kT[((size_t)b * D_ + d) * LP1 + j] = tile[tx][ty + q * 8];
    }
}

// ---------------- attention core: 32-lane group per head, j-register tile ----------
__global__ __launch_bounds__(256)
void k_attn(const float* __restrict__ qkv, const float* __restrict__ kT,
            const float* __restrict__ s_norm, const float* __restrict__ table,
            float* __restrict__ a) {
    const int m = blockIdx.x;
    const int b = m / LP1;
    const int i = m % LP1;
    const int t = threadIdx.x;
    __shared__ float q_s[D_];
    __shared__ float s_s[LP1 + 3];
    __shared__ float p_s[H_][LP1 + 3];

    q_s[t]       = qkv[(size_t)m * (3 * D_) + t];
    q_s[t + 256] = qkv[(size_t)m * (3 * D_) + t + 256];
    for (int j = t; j < LP1; j += 256)
        s_s[j] = (j == 0) ? 0.f : s_norm[b * L_ + j - 1];
    const float s_i = (i == 0) ? 0.f : s_norm[b * L_ + i - 1];
    __syncthreads();

    const int g  = t >> 5;    // head
    const int sl = t & 31;    // lane in group
    constexpr int NJ = 17;    // ceil(513/32)

    float acc[NJ];
    #pragma unroll
    for (int jj = 0; jj < NJ; ++jj) acc[jj] = 0.f;
    const float* kTg = kT + ((size_t)b * D_ + g * HD_) * LP1;
    for (int dd = 0; dd < HD_; ++dd) {
        const float qv = q_s[g * HD_ + dd];
        const float* row = kTg + (size_t)dd * LP1;
        #pragma unroll
        for (int jj = 0; jj < NJ; ++jj) {
            const int j = sl + jj * 32;
            const float kv = (j < LP1) ? row[j] : 0.f;
            acc[jj] = fmaf(qv, kv, acc[jj]);
        }
    }

    float mx = -1e30f;
    #pragma unroll
    for (int jj = 0; jj < NJ; ++jj) {
        const int j = sl + jj * 32;
        if (j < LP1) {
            const float ds = s_i - s_s[j];
            float u = (ds + 1.0f) * ((NT_ - 1) * 0.5f);
            u = fminf(fmaxf(u, 0.0f), (float)(NT_ - 2));
            const int i0 = (int)u;
            const float f = u - (float)i0;
            const float b0  = table[(size_t)i0 * H_ + g];
            const float b1v = table[(size_t)(i0 + 1) * H_ + g];
            acc[jj] = b0 + f * (b1v - b0) + 0.125f * acc[jj];
            mx = fmaxf(mx, acc[jj]);
        }
    }
    #pragma unroll
    for (int off = 16; off > 0; off >>= 1) mx = fmaxf(mx, __shfl_xor(mx, off, 32));
    float sum = 0.f;
    #pragma unroll
    for (int jj = 0; jj < NJ; ++jj) {
        const int j = sl + jj * 32;
        if (j < LP1) {
            acc[jj] = __expf(acc[jj] - mx);
            sum += acc[jj];
        }
    }
    #pragma unroll
    for (int off = 16; off > 0; off >>= 1) sum += __shfl_xor(sum, off, 32);
    const float inv = 1.0f / sum;
    #pragma unroll
    for (int jj = 0; jj < NJ; ++jj) {
        const int j = sl + jj * 32;
        if (j < LP1) p_s[g][j] = acc[jj] * inv;
    }
    __syncthreads();

    const float* vbase = qkv + (size_t)(b * LP1) * (3 * D_) + 2 * D_;
    for (int e = t; e < D_; e += 256) {
        const int h = e >> 6;
        float a0 = 0.f, a1 = 0.f, a2 = 0.f, a3 = 0.f;
        int j = 0;
        for (; j + 4 <= LP1; j += 4) {
            a0 = fmaf(p_s[h][j + 0], vbase[(size_t)(j + 0) * (3 * D_) + e], a0);
            a1 = fmaf(p_s[h][j + 1], vbase[(size_t)(j + 1) * (3 * D_) + e], a1);
            a2 = fmaf(p_s[h][j + 2], vbase[(size_t)(j + 2) * (3 * D_) + e], a2);
            a3 = fmaf(p_s[h][j + 3], vbase[(size_t)(j + 3) * (3 * D_) + e], a3);
        }
        for (; j < LP1; ++j)
            a0 = fmaf(p_s[h][j], vbase[(size_t)j * (3 * D_) + e], a0);
        a[(size_t)m * D_ + e] = (a0 + a1) + (a2 + a3);
    }
}

extern "C" void kernel_launch(void* const* d_in, const int* in_sizes, int n_in,
                              void* d_out, int out_size, void* d_ws, size_t ws_size,
                              hipStream_t stream) {
    const float* x      = (const float*)d_in[0];
    const float* s_norm = (const float*)d_in[1];
    const float* rff    = (const float*)d_in[2];
    const float* rb_w1  = (const float*)d_in[3];
    const float* rb_b1  = (const float*)d_in[4];
    const float* rb_w2  = (const float*)d_in[5];
    const float* rb_b2  = (const float*)d_in[6];
    const float* n1_g   = (const float*)d_in[7];
    const float* n1_b   = (const float*)d_in[8];
    const float* n2_g   = (const float*)d_in[9];
    const float* n2_b   = (const float*)d_in[10];
    const float* in_w   = (const float*)d_in[11];
    const float* in_b   = (const float*)d_in[12];
    const float* out_w  = (const float*)d_in[13];
    const float* out_b  = (const float*)d_in[14];
    const float* ff_w1  = (const float*)d_in[15];
    const float* ff_b1  = (const float*)d_in[16];
    const float* ff_w2  = (const float*)d_in[17];
    const float* ff_b2  = (const float*)d_in[18];

    float* ws    = (float*)d_ws;
    float* z     = ws + OFFZ;      // reused as h2
    float* x1    = ws + OFFX1;
    float* qkv   = ws + OFFQKV;
    float* kT    = ws + OFFKT;
    float* a     = ws + OFFA;
    float* table = ws + OFFT;
    float* h2    = z;
    float* hact  = qkv;            // overlays qkv+kT (both dead by FF phase)

    // 0) bias table
    k_btab<<<(NT_ + 255) / 256, 256, 0, stream>>>(rff, rb_w1, rb_b1, rb_w2, rb_b2, table);
    // 1) LN1 -> z
    k_ln<<<M_, 256, 0, stream>>>(x, n1_g, n1_b, z);
    // 2) qkv = z @ in_w^T + in_b
    k_gemm_mfma<0, false><<<dim3(3 * D_ / 64, (M_ + 63) / 64), 256, 0, stream>>>(
        z, in_w, in_b, nullptr, qkv, M_, 3 * D_, D_);
    // 3) kT = transpose of K part
    k_kT<<<dim3((LP1 + 31) / 32, D_ / 32, B_), dim3(32, 8), 0, stream>>>(qkv, kT);
    // 4) attention core -> a
    k_attn<<<M_, 256, 0, stream>>>(qkv, kT, s_norm, table, a);
    // 5) x1 = x + a @ out_w^T + out_b
    k_gemm_mfma<0, true><<<dim3(D_ / 64, (M_ + 63) / 64), 256, 0, stream>>>(
        a, out_w, out_b, x, x1, M_, D_, D_);
    // 6) LN2 -> h2
    k_ln<<<M_, 256, 0, stream>>>(x1, n2_g, n2_b, h2);
    // 7) hact = gelu(h2 @ ff_w1^T + ff_b1)
    k_gemm_mfma<1, false><<<dim3(FF_ / 64, (M_ + 63) / 64), 256, 0, stream>>>(
        h2, ff_w1, ff_b1, nullptr, hact, M_, FF_, D_);
    // 8) out = x1 + hact @ ff_w2^T + ff_b2
    k_gemm_mfma<0, true><<<dim3(D_ / 64, (M_ + 63) / 64), 256, 0, stream>>>(
        hact, ff_w2, ff_b2, x1, (float*)d_out, M_, D_, FF_);
}